// Round 1
// baseline (915.575 us; speedup 1.0000x reference)
//
#include <hip/hip_runtime.h>
#include <hip/hip_bf16.h>

#define BATCH 128
#define TSEQ  256
#define NEMBD 384
#define NHEAD 6
#define HDIM  64
#define C3    (3 * NEMBD)   // 1152

// ---------- helpers ----------

__device__ __forceinline__ float bf2f(unsigned short u) {
  union { unsigned int i; float f; } x;
  x.i = ((unsigned int)u) << 16;
  return x.f;
}

__device__ __forceinline__ unsigned short f2bf(float f) {
  __hip_bfloat16 h = __float2bfloat16(f);   // RNE
  unsigned short u;
  __builtin_memcpy(&u, &h, 2);
  return u;
}

__device__ __forceinline__ void store4(float* p, float a, float b, float c, float d) {
  *reinterpret_cast<float4*>(p) = make_float4(a, b, c, d);
}

__device__ __forceinline__ void store4(__hip_bfloat16* p, float a, float b, float c, float d) {
  ushort4 v;
  v.x = f2bf(a); v.y = f2bf(b); v.z = f2bf(c); v.w = f2bf(d);
  *reinterpret_cast<ushort4*>(p) = v;
}

// ---------- fp32 tiled GEMM: C(MxN) = A(MxK) @ B(KxN) ----------
// 64x64 tile, BK=16, 256 threads, 4x4 micro-tile per thread.
// Requires M%64==0, N%64==0, K%16==0 (true for all our shapes).

template <typename TC>
__global__ __launch_bounds__(256)
void gemm64(const float* __restrict__ A, const float* __restrict__ B,
            TC* __restrict__ C, int M, int N, int K) {
  __shared__ float As[16][64];   // As[k][m]
  __shared__ float Bs[16][64];   // Bs[k][n]

  const int tid = threadIdx.x;
  const int tx = tid & 15;       // -> 4 output cols
  const int ty = tid >> 4;       // -> 4 output rows
  const int m0 = blockIdx.y * 64;
  const int n0 = blockIdx.x * 64;

  // A-tile load map: 64 rows x 16 k, one float4 per thread
  const int am = tid >> 2;           // 0..63
  const int ak = (tid & 3) * 4;      // 0,4,8,12
  // B-tile load map: 16 k x 64 n, one float4 per thread
  const int bk = tid >> 4;           // 0..15
  const int bn = (tid & 15) * 4;     // 0..60

  const float* Ap = A + (size_t)(m0 + am) * K + ak;
  const float* Bp = B + (size_t)bk * N + n0 + bn;

  float acc[4][4] = {};

  for (int k0 = 0; k0 < K; k0 += 16) {
    float4 av = *reinterpret_cast<const float4*>(Ap + k0);
    float4 bv = *reinterpret_cast<const float4*>(Bp + (size_t)k0 * N);
    __syncthreads();               // previous iter's reads done before overwrite
    As[ak + 0][am] = av.x;
    As[ak + 1][am] = av.y;
    As[ak + 2][am] = av.z;
    As[ak + 3][am] = av.w;
    *reinterpret_cast<float4*>(&Bs[bk][bn]) = bv;
    __syncthreads();
#pragma unroll
    for (int kk = 0; kk < 16; ++kk) {
      float4 a = *reinterpret_cast<const float4*>(&As[kk][ty * 4]);
      float4 b = *reinterpret_cast<const float4*>(&Bs[kk][tx * 4]);
      float ar[4] = {a.x, a.y, a.z, a.w};
      float br[4] = {b.x, b.y, b.z, b.w};
#pragma unroll
      for (int i = 0; i < 4; ++i)
#pragma unroll
        for (int j = 0; j < 4; ++j)
          acc[i][j] = fmaf(ar[i], br[j], acc[i][j]);
    }
  }

#pragma unroll
  for (int i = 0; i < 4; ++i) {
    const int row = m0 + ty * 4 + i;
    const int col = n0 + tx * 4;
    store4(C + (size_t)row * N + col, acc[i][0], acc[i][1], acc[i][2], acc[i][3]);
  }
}

// ---------- causal attention, one block per (b,h), one thread per query ----------
// qkv layout (from GEMM): row (b*256+t), cols [0:384)=K, [384:768)=Q, [768:1152)=V
// NOTE reference quirk: scale = 1/sqrt(384) (full embed dim), split order K,Q,V.

__global__ __launch_bounds__(256)
void attn(const __hip_bfloat16* __restrict__ qkv, float* __restrict__ O) {
  const int bh = blockIdx.x;
  const int b  = bh / NHEAD;
  const int h  = bh % NHEAD;
  const int tid = threadIdx.x;
  const int q = tid;                 // one query per thread

  __shared__ float Ks[64][64];
  __shared__ float Vs[64][64];

  const unsigned short* qkvu = reinterpret_cast<const unsigned short*>(qkv);

  // Q row -> registers
  float Qr[64];
  {
    const ushort4* qp = reinterpret_cast<const ushort4*>(
        qkvu + (size_t)(b * TSEQ + q) * C3 + NEMBD + h * HDIM);
#pragma unroll
    for (int j4 = 0; j4 < 16; ++j4) {
      ushort4 u = qp[j4];
      Qr[4 * j4 + 0] = bf2f(u.x);
      Qr[4 * j4 + 1] = bf2f(u.y);
      Qr[4 * j4 + 2] = bf2f(u.z);
      Qr[4 * j4 + 3] = bf2f(u.w);
    }
  }

  float m = -INFINITY, l = 0.f;
  float acc[64];
#pragma unroll
  for (int j = 0; j < 64; ++j) acc[j] = 0.f;

  const float scale = 0.051031036307982884f;  // 1/sqrt(384)

  for (int c = 0; c < 4; ++c) {
    __syncthreads();
    // stage 64 keys + values: thread t -> col (t&63), rows (t>>6)*16 .. +15
    const int colg  = tid & 63;
    const int rbase = (tid >> 6) * 16;
    const unsigned short* Kg =
        qkvu + (size_t)(b * TSEQ + c * 64 + rbase) * C3 + h * HDIM + colg;
#pragma unroll
    for (int rr = 0; rr < 16; ++rr) {
      Ks[rbase + rr][colg] = bf2f(Kg[(size_t)rr * C3]);
      Vs[rbase + rr][colg] = bf2f(Kg[(size_t)rr * C3 + 2 * NEMBD]);
    }
    __syncthreads();

    if (q >= c * 64) {               // whole-wave execz skip for future chunks
      const int kmax = min(63, q - c * 64);
      for (int kl = 0; kl <= kmax; ++kl) {
        float s0 = 0.f, s1 = 0.f, s2 = 0.f, s3 = 0.f;
#pragma unroll
        for (int j = 0; j < 64; j += 4) {      // wave-uniform LDS broadcast
          s0 = fmaf(Qr[j + 0], Ks[kl][j + 0], s0);
          s1 = fmaf(Qr[j + 1], Ks[kl][j + 1], s1);
          s2 = fmaf(Qr[j + 2], Ks[kl][j + 2], s2);
          s3 = fmaf(Qr[j + 3], Ks[kl][j + 3], s3);
        }
        const float s = ((s0 + s1) + (s2 + s3)) * scale;
        const float mn   = fmaxf(m, s);
        const float corr = __expf(m - mn);     // m=-inf first iter -> corr=0
        const float p    = __expf(s - mn);
        l = l * corr + p;
#pragma unroll
        for (int j = 0; j < 64; ++j)
          acc[j] = fmaf(acc[j], corr, p * Vs[kl][j]);
        m = mn;
      }
    }
  }

  const float inv = 1.f / l;
  float* Op = O + (size_t)(b * TSEQ + q) * NEMBD + h * HDIM;
#pragma unroll
  for (int j = 0; j < 64; j += 4)
    store4(Op + j, acc[j] * inv, acc[j + 1] * inv, acc[j + 2] * inv, acc[j + 3] * inv);
}

// ---------- launch ----------

extern "C" void kernel_launch(void* const* d_in, const int* in_sizes, int n_in,
                              void* d_out, int out_size, void* d_ws, size_t ws_size,
                              hipStream_t stream) {
  const float* X     = (const float*)d_in[0];   // (128,256,384)
  const float* Wqkv  = (const float*)d_in[1];   // (384,1152)
  const float* Wproj = (const float*)d_in[2];   // (384,384)
  float* out = (float*)d_out;                   // (128,256,384)

  const int M  = BATCH * TSEQ;   // 32768
  const int K  = NEMBD;          // 384
  const int N1 = C3;             // 1152
  const int N2 = NEMBD;          // 384

  // workspace: qkv bf16 (75.5 MB) | O fp32 (50.3 MB)  => 120 MB total
  __hip_bfloat16* qkv = (__hip_bfloat16*)d_ws;
  const size_t qkv_bytes = (size_t)M * N1 * sizeof(__hip_bfloat16);
  float* O = (float*)((char*)d_ws + qkv_bytes);

  dim3 block(256);
  gemm64<__hip_bfloat16><<<dim3(N1 / 64, M / 64), block, 0, stream>>>(X, Wqkv, qkv, M, N1, K);
  attn<<<dim3(BATCH * NHEAD), block, 0, stream>>>(qkv, O);
  gemm64<float><<<dim3(N2 / 64, M / 64), block, 0, stream>>>(O, Wproj, out, M, N2, K);
}

// Round 2
// 506.348 us; speedup vs baseline: 1.8082x; 1.8082x over previous
//
#include <hip/hip_runtime.h>
#include <hip/hip_bf16.h>

#define BATCH 128
#define TSEQ  256
#define NEMBD 384
#define NHEAD 6
#define HDIM  64
#define C3    1152
#define MROWS 32768      // BATCH*TSEQ
#define KGTOT 48         // NEMBD/8

typedef __attribute__((ext_vector_type(8))) short short8v;
typedef __attribute__((ext_vector_type(4))) float float4v;

// ---------- helpers ----------

__device__ __forceinline__ float bf2f(unsigned short u) {
  union { unsigned int i; float f; } x;
  x.i = ((unsigned int)u) << 16;
  return x.f;
}

__device__ __forceinline__ unsigned short f2bf(float f) {
  __hip_bfloat16 h = __float2bfloat16(f);   // RNE
  unsigned short u;
  __builtin_memcpy(&u, &h, 2);
  return u;
}

// ---------- X fp32 -> bf16, tiled [m/128][k/8][128][8] ----------
__global__ __launch_bounds__(256)
void convertA(const float* __restrict__ X, unsigned short* __restrict__ out) {
  const int idx = blockIdx.x * 256 + threadIdx.x;   // chunk id, MROWS*KGTOT total
  const int ml  = idx & 127;
  const int kgg = (idx >> 7) % KGTOT;
  const int mb  = idx / (128 * KGTOT);
  const float* src = X + ((size_t)(mb * 128 + ml) * NEMBD + kgg * 8);
  float4 a = *reinterpret_cast<const float4*>(src);
  float4 b = *reinterpret_cast<const float4*>(src + 4);
  short8v v;
  v[0] = (short)f2bf(a.x); v[1] = (short)f2bf(a.y);
  v[2] = (short)f2bf(a.z); v[3] = (short)f2bf(a.w);
  v[4] = (short)f2bf(b.x); v[5] = (short)f2bf(b.y);
  v[6] = (short)f2bf(b.z); v[7] = (short)f2bf(b.w);
  *reinterpret_cast<short8v*>(out + (size_t)idx * 8) = v;
}

// ---------- W (KxN fp32, row-major) -> bf16 transposed-tiled [n/128][k/8][128][8] ----------
__global__ __launch_bounds__(256)
void convertB(const float* __restrict__ W, unsigned short* __restrict__ out, int N) {
  const int idx = blockIdx.x * 256 + threadIdx.x;   // chunk id, N*KGTOT total
  const int nl  = idx & 127;
  const int kgg = (idx >> 7) % KGTOT;
  const int nb  = idx / (128 * KGTOT);
  const int n = nb * 128 + nl;
  short8v v;
#pragma unroll
  for (int j = 0; j < 8; ++j)
    v[j] = (short)f2bf(W[(size_t)(kgg * 8 + j) * N + n]);
  *reinterpret_cast<short8v*>(out + (size_t)idx * 8) = v;
}

// ---------- bf16 MFMA GEMM: C(MxN) = A @ B ----------
// A: [M/128][K/8][128][8] bf16 tiled.  B: [N/128][K/8][128][8] bf16 tiled (transposed).
// 128x128 tile, BK=32, 256 threads = 4 waves, each wave a 64x64 quadrant of 4x4
// 16x16x32 fragments. global_load_lds width-16 staging; LDS layout == lane order
// (wave-uniform base + lane*16), giving 2-way (free) bank aliasing on ds_read_b128.

__device__ __forceinline__ void store_c(float* p, float v)          { *p = v; }
__device__ __forceinline__ void store_c(unsigned short* p, float v) { *p = f2bf(v); }

template <typename TC>
__global__ __launch_bounds__(256)
void gemm_mfma(const unsigned short* __restrict__ A,
               const unsigned short* __restrict__ B,
               TC* __restrict__ C, int N) {
  __shared__ __attribute__((aligned(16))) unsigned short Asl[4096];  // [4 kg][128 m][8]
  __shared__ __attribute__((aligned(16))) unsigned short Bsl[4096];  // [4 kg][128 n][8]

  const int tid   = threadIdx.x;
  const int wave  = tid >> 6;
  const int lane  = tid & 63;
  const int mtile = blockIdx.y;
  const int ntile = blockIdx.x;

  const unsigned short* Ab = A + (size_t)mtile * (KGTOT * 128 * 8);
  const unsigned short* Bb = B + (size_t)ntile * (KGTOT * 128 * 8);

  const int wm  = (wave & 1) * 64;
  const int wn  = (wave >> 1) * 64;
  const int l15 = lane & 15;
  const int lq  = lane >> 4;

  float4v acc[4][4];
#pragma unroll
  for (int i = 0; i < 4; ++i)
#pragma unroll
    for (int j = 0; j < 4; ++j) acc[i][j] = (float4v){0.f, 0.f, 0.f, 0.f};

  const int ldsb0 = wave * 64 * 8;   // ushort offset, wave-uniform

  for (int kb = 0; kb < KGTOT / 4; ++kb) {
    __syncthreads();
#pragma unroll
    for (int r = 0; r < 2; ++r) {
      const int i = r * 256 + tid;                               // chunk 0..511
      const size_t goff = ((size_t)(kb * 4 + (i >> 7)) * 128 + (i & 127)) * 8;
      const int lb = ldsb0 + r * 2048;
      __builtin_amdgcn_global_load_lds(
          (const __attribute__((address_space(1))) unsigned int*)(Ab + goff),
          (__attribute__((address_space(3))) unsigned int*)(Asl + lb), 16, 0, 0);
      __builtin_amdgcn_global_load_lds(
          (const __attribute__((address_space(1))) unsigned int*)(Bb + goff),
          (__attribute__((address_space(3))) unsigned int*)(Bsl + lb), 16, 0, 0);
    }
    __syncthreads();   // drains vmcnt before barrier

    short8v af[4], bfr[4];
#pragma unroll
    for (int mi = 0; mi < 4; ++mi)
      af[mi] = *reinterpret_cast<const short8v*>(Asl + (size_t)(lq * 128 + wm + mi * 16 + l15) * 8);
#pragma unroll
    for (int ni = 0; ni < 4; ++ni)
      bfr[ni] = *reinterpret_cast<const short8v*>(Bsl + (size_t)(lq * 128 + wn + ni * 16 + l15) * 8);
#pragma unroll
    for (int mi = 0; mi < 4; ++mi)
#pragma unroll
      for (int ni = 0; ni < 4; ++ni)
        acc[mi][ni] = __builtin_amdgcn_mfma_f32_16x16x32_bf16(af[mi], bfr[ni], acc[mi][ni], 0, 0, 0);
  }

  // C/D layout: col = lane&15, row = (lane>>4)*4 + reg  (guide §3, HW-verified m89/m91)
  const int colbase = ntile * 128 + wn + l15;
  const int rowbase = mtile * 128 + wm + lq * 4;
#pragma unroll
  for (int mi = 0; mi < 4; ++mi)
#pragma unroll
    for (int ni = 0; ni < 4; ++ni)
#pragma unroll
      for (int r = 0; r < 4; ++r)
        store_c(C + (size_t)(rowbase + mi * 16 + r) * N + colbase + ni * 16, acc[mi][ni][r]);
}

// ---------- causal attention, one block per (b,h), one thread per query ----------
// qkv layout: row (b*256+t) x 1152 bf16; cols [0:384)=K, [384:768)=Q, [768:1152)=V
// Reference quirks: split order K,Q,V; scale = 1/sqrt(384).
// Output written bf16 directly into GEMM-A tiled layout [m/128][k/8][128][8].

__global__ __launch_bounds__(256)
void attn(const unsigned short* __restrict__ qkv, unsigned short* __restrict__ Obf) {
  const int bh = blockIdx.x;
  const int b  = bh / NHEAD;
  const int h  = bh % NHEAD;
  const int tid = threadIdx.x;
  const int q = tid;

  __shared__ float Ks[64][64];
  __shared__ float Vs[64][64];

  const float scale = 0.051031036307982884f;  // 1/sqrt(384)

  float Qr[64];
  {
    const ushort4* qp = reinterpret_cast<const ushort4*>(
        qkv + (size_t)(b * TSEQ + q) * C3 + NEMBD + h * HDIM);
#pragma unroll
    for (int j4 = 0; j4 < 16; ++j4) {
      ushort4 u = qp[j4];
      Qr[4 * j4 + 0] = bf2f(u.x) * scale;
      Qr[4 * j4 + 1] = bf2f(u.y) * scale;
      Qr[4 * j4 + 2] = bf2f(u.z) * scale;
      Qr[4 * j4 + 3] = bf2f(u.w) * scale;
    }
  }

  float m = -INFINITY, l = 0.f;
  float acc[64];
#pragma unroll
  for (int j = 0; j < 64; ++j) acc[j] = 0.f;

  for (int c = 0; c < 4; ++c) {
    __syncthreads();
    const int colg  = tid & 63;
    const int rbase = (tid >> 6) * 16;
    const unsigned short* Kg =
        qkv + (size_t)(b * TSEQ + c * 64 + rbase) * C3 + h * HDIM + colg;
#pragma unroll
    for (int rr = 0; rr < 16; ++rr) {
      Ks[rbase + rr][colg] = bf2f(Kg[(size_t)rr * C3]);
      Vs[rbase + rr][colg] = bf2f(Kg[(size_t)rr * C3 + 2 * NEMBD]);
    }
    __syncthreads();

    if (q >= c * 64) {
      const int kmax = min(63, q - c * 64);
      for (int kl = 0; kl <= kmax; ++kl) {
        const float4* Kr = reinterpret_cast<const float4*>(&Ks[kl][0]);
        float s0 = 0.f, s1 = 0.f, s2 = 0.f, s3 = 0.f;
#pragma unroll
        for (int jj = 0; jj < 16; ++jj) {      // wave-uniform b128 broadcast
          float4 kv = Kr[jj];
          s0 = fmaf(Qr[4 * jj + 0], kv.x, s0);
          s1 = fmaf(Qr[4 * jj + 1], kv.y, s1);
          s2 = fmaf(Qr[4 * jj + 2], kv.z, s2);
          s3 = fmaf(Qr[4 * jj + 3], kv.w, s3);
        }
        const float s = (s0 + s1) + (s2 + s3);
        const float mn   = fmaxf(m, s);
        const float corr = __expf(m - mn);
        const float p    = __expf(s - mn);
        l = l * corr + p;
        const float4* Vr = reinterpret_cast<const float4*>(&Vs[kl][0]);
#pragma unroll
        for (int jj = 0; jj < 16; ++jj) {
          float4 vv = Vr[jj];
          acc[4 * jj + 0] = fmaf(acc[4 * jj + 0], corr, p * vv.x);
          acc[4 * jj + 1] = fmaf(acc[4 * jj + 1], corr, p * vv.y);
          acc[4 * jj + 2] = fmaf(acc[4 * jj + 2], corr, p * vv.z);
          acc[4 * jj + 3] = fmaf(acc[4 * jj + 3], corr, p * vv.w);
        }
        m = mn;
      }
    }
  }

  const float inv = 1.f / l;
  const int row = b * TSEQ + q;
  unsigned short* Op = Obf + ((size_t)(row >> 7) * KGTOT + h * 8) * (128 * 8)
                           + (size_t)(row & 127) * 8;
#pragma unroll
  for (int jc = 0; jc < 8; ++jc) {
    short8v v;
#pragma unroll
    for (int j = 0; j < 8; ++j) v[j] = (short)f2bf(acc[jc * 8 + j] * inv);
    *reinterpret_cast<short8v*>(Op + (size_t)jc * (128 * 8)) = v;
  }
}

// ---------- launch ----------

extern "C" void kernel_launch(void* const* d_in, const int* in_sizes, int n_in,
                              void* d_out, int out_size, void* d_ws, size_t ws_size,
                              hipStream_t stream) {
  const float* X     = (const float*)d_in[0];   // (128,256,384)
  const float* Wqkv  = (const float*)d_in[1];   // (384,1152)
  const float* Wproj = (const float*)d_in[2];   // (384,384)
  float* out = (float*)d_out;

  // ws layout (bytes):
  //   qkv bf16 row-major [32768][1152]                : 75,497,472
  //   Abf (X bf16 tiled) — reused as Obf after QKV GEMM: 25,165,824
  //   WqkvT bf16 tiled                                 :    884,736
  //   WprojT bf16 tiled                                :    294,912
  unsigned short* qkv    = (unsigned short*)d_ws;
  unsigned short* Abf    = (unsigned short*)((char*)d_ws + 75497472);
  unsigned short* WqkvT  = (unsigned short*)((char*)d_ws + 75497472 + 25165824);
  unsigned short* WprojT = (unsigned short*)((char*)d_ws + 75497472 + 25165824 + 884736);
  unsigned short* Obf    = Abf;   // alias: Abf fully consumed before attn writes

  dim3 blk(256);
  convertA<<<dim3((MROWS * KGTOT) / 256), blk, 0, stream>>>(X, Abf);
  convertB<<<dim3((C3 * KGTOT) / 256), blk, 0, stream>>>(Wqkv, WqkvT, C3);
  convertB<<<dim3((NEMBD * KGTOT) / 256), blk, 0, stream>>>(Wproj, WprojT, NEMBD);

  gemm_mfma<unsigned short><<<dim3(C3 / 128, MROWS / 128), blk, 0, stream>>>(Abf, WqkvT, qkv, C3);
  attn<<<dim3(BATCH * NHEAD), blk, 0, stream>>>(qkv, Obf);
  gemm_mfma<float><<<dim3(NEMBD / 128, MROWS / 128), blk, 0, stream>>>(Obf, WprojT, out, NEMBD);
}

// Round 3
// 256.629 us; speedup vs baseline: 3.5677x; 1.9731x over previous
//
#include <hip/hip_runtime.h>
#include <hip/hip_bf16.h>

#define BATCH 128
#define TSEQ  256
#define NEMBD 384
#define NHEAD 6
#define HDIM  64
#define C3    1152
#define MROWS 32768      // BATCH*TSEQ
#define KGTOT 48         // NEMBD/8
#define NBH   768        // BATCH*NHEAD

typedef __attribute__((ext_vector_type(8))) short short8v;
typedef __attribute__((ext_vector_type(4))) float float4v;

// ---------- helpers ----------

__device__ __forceinline__ float bf2f(unsigned short u) {
  union { unsigned int i; float f; } x;
  x.i = ((unsigned int)u) << 16;
  return x.f;
}

__device__ __forceinline__ unsigned short f2bf(float f) {
  __hip_bfloat16 h = __float2bfloat16(f);   // RNE
  unsigned short u;
  __builtin_memcpy(&u, &h, 2);
  return u;
}

// ---------- X fp32 -> bf16, tiled [m/128][k/8][128][8] ----------
__global__ __launch_bounds__(256)
void convertA(const float* __restrict__ X, unsigned short* __restrict__ out) {
  const int idx = blockIdx.x * 256 + threadIdx.x;
  const int ml  = idx & 127;
  const int kgg = (idx >> 7) % KGTOT;
  const int mb  = idx / (128 * KGTOT);
  const float* src = X + ((size_t)(mb * 128 + ml) * NEMBD + kgg * 8);
  float4 a = *reinterpret_cast<const float4*>(src);
  float4 b = *reinterpret_cast<const float4*>(src + 4);
  short8v v;
  v[0] = (short)f2bf(a.x); v[1] = (short)f2bf(a.y);
  v[2] = (short)f2bf(a.z); v[3] = (short)f2bf(a.w);
  v[4] = (short)f2bf(b.x); v[5] = (short)f2bf(b.y);
  v[6] = (short)f2bf(b.z); v[7] = (short)f2bf(b.w);
  *reinterpret_cast<short8v*>(out + (size_t)idx * 8) = v;
}

// ---------- W (KxN fp32) -> bf16 transposed-tiled [n/128][k/8][128][8] ----------
__global__ __launch_bounds__(256)
void convertB(const float* __restrict__ W, unsigned short* __restrict__ out, int N) {
  const int idx = blockIdx.x * 256 + threadIdx.x;
  const int nl  = idx & 127;
  const int kgg = (idx >> 7) % KGTOT;
  const int nb  = idx / (128 * KGTOT);
  const int n = nb * 128 + nl;
  short8v v;
#pragma unroll
  for (int j = 0; j < 8; ++j)
    v[j] = (short)f2bf(W[(size_t)(kgg * 8 + j) * N + n]);
  *reinterpret_cast<short8v*>(out + (size_t)idx * 8) = v;
}

// ---------- shared GEMM core macro: stages A/B tiles, accumulates 4x4 frags ----------
// A: [M/128][K/8][128][8] bf16, B: [N/128][K/8][128][8] bf16. 256 thr = 4 waves.

#define GEMM_CORE(Ab, Bb)                                                              \
  __shared__ __attribute__((aligned(16))) unsigned short Asl[4096];                    \
  __shared__ __attribute__((aligned(16))) unsigned short Bsl[4096];                    \
  const int tid  = threadIdx.x;                                                        \
  const int wave = tid >> 6;                                                           \
  const int lane = tid & 63;                                                           \
  const int wm  = (wave & 1) * 64;                                                     \
  const int wn  = (wave >> 1) * 64;                                                    \
  const int l15 = lane & 15;                                                           \
  const int lq  = lane >> 4;                                                           \
  float4v acc[4][4];                                                                   \
  _Pragma("unroll") for (int i = 0; i < 4; ++i)                                        \
    _Pragma("unroll") for (int j = 0; j < 4; ++j)                                      \
      acc[i][j] = (float4v){0.f, 0.f, 0.f, 0.f};                                       \
  const int ldsb0 = wave * 64 * 8;                                                     \
  for (int kb = 0; kb < KGTOT / 4; ++kb) {                                             \
    __syncthreads();                                                                   \
    _Pragma("unroll") for (int r = 0; r < 2; ++r) {                                    \
      const int i = r * 256 + tid;                                                     \
      const size_t goff = ((size_t)(kb * 4 + (i >> 7)) * 128 + (i & 127)) * 8;         \
      const int lb = ldsb0 + r * 2048;                                                 \
      __builtin_amdgcn_global_load_lds(                                                \
          (const __attribute__((address_space(1))) unsigned int*)(Ab + goff),          \
          (__attribute__((address_space(3))) unsigned int*)(Asl + lb), 16, 0, 0);      \
      __builtin_amdgcn_global_load_lds(                                                \
          (const __attribute__((address_space(1))) unsigned int*)(Bb + goff),          \
          (__attribute__((address_space(3))) unsigned int*)(Bsl + lb), 16, 0, 0);      \
    }                                                                                  \
    __syncthreads();                                                                   \
    short8v af[4], bfr[4];                                                             \
    _Pragma("unroll") for (int mi = 0; mi < 4; ++mi)                                   \
      af[mi] = *reinterpret_cast<const short8v*>(                                      \
          Asl + (size_t)(lq * 128 + wm + mi * 16 + l15) * 8);                          \
    _Pragma("unroll") for (int ni = 0; ni < 4; ++ni)                                   \
      bfr[ni] = *reinterpret_cast<const short8v*>(                                     \
          Bsl + (size_t)(lq * 128 + wn + ni * 16 + l15) * 8);                          \
    _Pragma("unroll") for (int mi = 0; mi < 4; ++mi)                                   \
      _Pragma("unroll") for (int ni = 0; ni < 4; ++ni)                                 \
        acc[mi][ni] = __builtin_amdgcn_mfma_f32_16x16x32_bf16(af[mi], bfr[ni],         \
                                                              acc[mi][ni], 0, 0, 0);   \
  }

// ---------- QKV GEMM: writes K/Q/V scatter into [type][b][h][t][d] bf16 ----------
// split order (reference quirk): cols 0-383 = K, 384-767 = Q, 768-1151 = V.
// Q gets the 1/sqrt(384) softmax scale folded in here.
__global__ __launch_bounds__(256)
void gemm_qkv(const unsigned short* __restrict__ A,
              const unsigned short* __restrict__ B,
              unsigned short* __restrict__ KQV) {
  const int mtile = blockIdx.y;
  const int ntile = blockIdx.x;
  const unsigned short* Ab = A + (size_t)mtile * (KGTOT * 128 * 8);
  const unsigned short* Bb = B + (size_t)ntile * (KGTOT * 128 * 8);
  GEMM_CORE(Ab, Bb)
  // C/D layout: col = lane&15, row = (lane>>4)*4 + reg
  const int colb = ntile * 128 + wn + l15;
  const int rowb = mtile * 128 + wm + lq * 4;
#pragma unroll
  for (int ni = 0; ni < 4; ++ni) {
    const int col  = colb + ni * 16;
    const int type = (col >= 768) ? 2 : (col >= 384 ? 1 : 0);
    const int rem  = col - type * 384;
    const int hh   = rem >> 6;
    const int d    = rem & 63;
    const float sc = (type == 1) ? 0.051031036307982884f : 1.0f;
    unsigned short* outb = KQV + (size_t)type * NBH * (TSEQ * HDIM) + d;
#pragma unroll
    for (int mi = 0; mi < 4; ++mi) {
#pragma unroll
      for (int r = 0; r < 4; ++r) {
        const int m  = rowb + mi * 16 + r;
        const int bb = m >> 8;
        const int tt = m & 255;
        outb[((size_t)(bb * NHEAD + hh) * TSEQ + tt) * HDIM] = f2bf(acc[mi][ni][r] * sc);
      }
    }
  }
}

// ---------- proj GEMM: fp32 output, row-major ----------
__global__ __launch_bounds__(256)
void gemm_proj(const unsigned short* __restrict__ A,
               const unsigned short* __restrict__ B,
               float* __restrict__ C, int N) {
  const int mtile = blockIdx.y;
  const int ntile = blockIdx.x;
  const unsigned short* Ab = A + (size_t)mtile * (KGTOT * 128 * 8);
  const unsigned short* Bb = B + (size_t)ntile * (KGTOT * 128 * 8);
  GEMM_CORE(Ab, Bb)
  const int colbase = ntile * 128 + wn + l15;
  const int rowbase = mtile * 128 + wm + lq * 4;
#pragma unroll
  for (int mi = 0; mi < 4; ++mi)
#pragma unroll
    for (int ni = 0; ni < 4; ++ni)
#pragma unroll
      for (int r = 0; r < 4; ++r)
        C[(size_t)(rowbase + mi * 16 + r) * N + colbase + ni * 16] = acc[mi][ni][r];
}

// ---------- MFMA flash attention ----------
// Grid (qt=4, bh=768), 256 thr = 4 waves; wave w owns Q rows qt*64+w*16 .. +15.
// K,Q,V from KQV [type][bh][t][d] row-major bf16 (Q pre-scaled).
// O written bf16 into proj-GEMM A-tiled layout [m/128][k/8][128][8].

__global__ __launch_bounds__(256)
void attn_mfma(const unsigned short* __restrict__ KQV,
               unsigned short* __restrict__ Obf) {
  const int qt   = blockIdx.x;
  const int bh   = blockIdx.y;
  const int b    = bh / NHEAD;
  const int h    = bh - b * NHEAD;
  const int tid  = threadIdx.x;
  const int wave = tid >> 6;
  const int lane = tid & 63;
  const int l15  = lane & 15;
  const int lq   = lane >> 4;

  __shared__ __attribute__((aligned(16))) unsigned short Vt[4096];     // [kg][64 d][8]
  __shared__ __attribute__((aligned(16))) unsigned short Pt[4][1024];  // per-wave [kg][16 q][8]

  const unsigned short* Kb = KQV + (size_t)bh * (TSEQ * HDIM);
  const unsigned short* Qb = KQV + (size_t)(NBH + bh) * (TSEQ * HDIM);
  const unsigned short* Vb = KQV + (size_t)(2 * NBH + bh) * (TSEQ * HDIM);

  const int q0 = qt * 64 + wave * 16;

  // Q A-frags (Q pre-scaled by 1/sqrt(384))
  short8v qa[2];
#pragma unroll
  for (int s = 0; s < 2; ++s)
    qa[s] = *reinterpret_cast<const short8v*>(
        Qb + (size_t)(q0 + l15) * HDIM + s * 32 + lq * 8);

  float4v o[4];
#pragma unroll
  for (int nf = 0; nf < 4; ++nf) o[nf] = (float4v){0.f, 0.f, 0.f, 0.f};
  float4v mrow = (float4v){-INFINITY, -INFINITY, -INFINITY, -INFINITY};
  float4v lrow = (float4v){0.f, 0.f, 0.f, 0.f};

  for (int kt = 0; kt <= qt; ++kt) {
    __syncthreads();   // Vt from previous tile fully consumed
    // ---- transpose V tile into Vt[kg][d][8] (coalesced 2B gathers) ----
    {
      const int d   = tid & 63;
      const int kg0 = tid >> 6;
#pragma unroll
      for (int half = 0; half < 2; ++half) {
        const int kg = kg0 + half * 4;
        const unsigned short* vsrc = Vb + (size_t)(kt * 64 + kg * 8) * HDIM + d;
        short8v v;
#pragma unroll
        for (int j = 0; j < 8; ++j) v[j] = (short)vsrc[(size_t)j * HDIM];
        *reinterpret_cast<short8v*>(Vt + (kg * 64 + d) * 8) = v;
      }
    }
    __syncthreads();

    // ---- S = Q K^T (A=Q frags in regs, B=K frags direct from global) ----
    float4v sf[4];
#pragma unroll
    for (int nf = 0; nf < 4; ++nf) sf[nf] = (float4v){0.f, 0.f, 0.f, 0.f};
#pragma unroll
    for (int s = 0; s < 2; ++s) {
#pragma unroll
      for (int nf = 0; nf < 4; ++nf) {
        short8v kf = *reinterpret_cast<const short8v*>(
            Kb + (size_t)(kt * 64 + nf * 16 + l15) * HDIM + s * 32 + lq * 8);
        sf[nf] = __builtin_amdgcn_mfma_f32_16x16x32_bf16(qa[s], kf, sf[nf], 0, 0, 0);
      }
    }

    // ---- causal mask (diagonal tile only) ----
    if (kt == qt) {
      const int qrow = wave * 16 + lq * 4;
#pragma unroll
      for (int nf = 0; nf < 4; ++nf) {
        const int key = nf * 16 + l15;
#pragma unroll
        for (int r = 0; r < 4; ++r)
          if (key > qrow + r) sf[nf][r] = -INFINITY;
      }
    }

    // ---- online softmax (rows distributed over the 16 l15-lanes) ----
    float4v rm;
#pragma unroll
    for (int r = 0; r < 4; ++r)
      rm[r] = fmaxf(fmaxf(sf[0][r], sf[1][r]), fmaxf(sf[2][r], sf[3][r]));
#pragma unroll
    for (int off = 1; off <= 8; off <<= 1) {
#pragma unroll
      for (int r = 0; r < 4; ++r)
        rm[r] = fmaxf(rm[r], __shfl_xor(rm[r], off));
    }
    float4v mnew, corr, psum;
#pragma unroll
    for (int r = 0; r < 4; ++r) {
      mnew[r] = fmaxf(mrow[r], rm[r]);
      corr[r] = __expf(mrow[r] - mnew[r]);
      psum[r] = 0.f;
    }
#pragma unroll
    for (int nf = 0; nf < 4; ++nf)
#pragma unroll
      for (int r = 0; r < 4; ++r) {
        const float p = __expf(sf[nf][r] - mnew[r]);
        sf[nf][r] = p;
        psum[r] += p;
      }
#pragma unroll
    for (int off = 1; off <= 8; off <<= 1) {
#pragma unroll
      for (int r = 0; r < 4; ++r)
        psum[r] += __shfl_xor(psum[r], off);
    }
#pragma unroll
    for (int r = 0; r < 4; ++r) {
      lrow[r] = lrow[r] * corr[r] + psum[r];
      mrow[r] = mnew[r];
    }
#pragma unroll
    for (int nf = 0; nf < 4; ++nf)
#pragma unroll
      for (int r = 0; r < 4; ++r)
        o[nf][r] *= corr[r];

    // ---- P (bf16) -> per-wave Pt[kg][q][8] (A-chunk layout) ----
    unsigned short* Pw = Pt[wave];
#pragma unroll
    for (int nf = 0; nf < 4; ++nf) {
      const int kg  = nf * 2 + (l15 >> 3);
      const int pos = l15 & 7;
#pragma unroll
      for (int r = 0; r < 4; ++r)
        Pw[(kg * 16 + lq * 4 + r) * 8 + pos] = f2bf(sf[nf][r]);
    }

    // ---- O += P V ----
#pragma unroll
    for (int s = 0; s < 2; ++s) {
      short8v pa = *reinterpret_cast<const short8v*>(Pw + ((s * 4 + lq) * 16 + l15) * 8);
#pragma unroll
      for (int nf = 0; nf < 4; ++nf) {
        short8v vf = *reinterpret_cast<const short8v*>(
            Vt + ((s * 4 + lq) * 64 + nf * 16 + l15) * 8);
        o[nf] = __builtin_amdgcn_mfma_f32_16x16x32_bf16(pa, vf, o[nf], 0, 0, 0);
      }
    }
  }

  // ---- epilogue: O/l -> Obf tiled [m/128][g][128][8] ----
  float4v inv;
#pragma unroll
  for (int r = 0; r < 4; ++r) inv[r] = 1.f / lrow[r];
  const int tbase = qt * 64 + wave * 16 + lq * 4;
#pragma unroll
  for (int nf = 0; nf < 4; ++nf) {
    const int d   = nf * 16 + l15;
    const int g   = h * 8 + (d >> 3);
    const int pos = d & 7;
#pragma unroll
    for (int r = 0; r < 4; ++r) {
      const int m = b * TSEQ + tbase + r;
      Obf[((size_t)(m >> 7) * KGTOT + g) * 1024 + (size_t)(m & 127) * 8 + pos] =
          f2bf(o[nf][r] * inv[r]);
    }
  }
}

// ---------- launch ----------

extern "C" void kernel_launch(void* const* d_in, const int* in_sizes, int n_in,
                              void* d_out, int out_size, void* d_ws, size_t ws_size,
                              hipStream_t stream) {
  const float* X     = (const float*)d_in[0];   // (128,256,384)
  const float* Wqkv  = (const float*)d_in[1];   // (384,1152)
  const float* Wproj = (const float*)d_in[2];   // (384,384)
  float* out = (float*)d_out;

  // ws layout (bytes):
  //   KQV  bf16 [3][768][256][64]          : 75,497,472
  //   Abf  (X bf16 tiled) -> reused as Obf : 25,165,824
  //   WqkvT bf16 tiled                     :    884,736
  //   WprojT bf16 tiled                    :    294,912
  unsigned short* KQV    = (unsigned short*)d_ws;
  unsigned short* Abf    = (unsigned short*)((char*)d_ws + 75497472);
  unsigned short* WqkvT  = (unsigned short*)((char*)d_ws + 75497472 + 25165824);
  unsigned short* WprojT = (unsigned short*)((char*)d_ws + 75497472 + 25165824 + 884736);
  unsigned short* Obf    = Abf;   // alias: Abf fully consumed before attn writes

  dim3 blk(256);
  convertA<<<dim3((MROWS * KGTOT) / 256), blk, 0, stream>>>(X, Abf);
  convertB<<<dim3((C3 * KGTOT) / 256), blk, 0, stream>>>(Wqkv, WqkvT, C3);
  convertB<<<dim3((NEMBD * KGTOT) / 256), blk, 0, stream>>>(Wproj, WprojT, NEMBD);

  gemm_qkv<<<dim3(C3 / 128, MROWS / 128), blk, 0, stream>>>(Abf, WqkvT, KQV);
  attn_mfma<<<dim3(4, NBH), blk, 0, stream>>>(KQV, Obf);
  gemm_proj<<<dim3(NEMBD / 128, MROWS / 128), blk, 0, stream>>>(Obf, WprojT, out, NEMBD);
}